// Round 7
// baseline (527.730 us; speedup 1.0000x reference)
//
#include <hip/hip_runtime.h>
#include <hip/hip_bf16.h>
#include <math.h>

#define BB 32
#define SS 512
#define EE 300
#define FF 100
#define TT 50
#define CH 16            // steps per chunk-product (15 multiplies, overflow-safe)
#define NC 32            // chunks = 512/16

typedef __attribute__((ext_vector_type(8))) short v8s;   // 8 bf16
typedef __attribute__((ext_vector_type(4))) float v4f;   // 4 f32
#define MFMA16 __builtin_amdgcn_mfma_f32_16x16x32_bf16

#define AP 328           // emb LDS stride (shorts): 2-way max (free)
#define NCH 10           // conv K-chunks of 96
#define CKS 3            // k-steps per chunk
#define CHB (128 * 96)   // shorts per conv B chunk buffer (24576 B)
#define A2P 136          // feat LDS stride (shorts)
#define MP 72            // chunk-product LDS row stride (bf16)
#define MAGICU 0x13572468u

__device__ inline unsigned short f2bf(float v) {
    unsigned u = __float_as_uint(v);
    unsigned r = u + 0x7fff + ((u >> 16) & 1);
    return (unsigned short)(r >> 16);
}
__device__ inline float bf2f(short s) {
    return __uint_as_float(((unsigned)(unsigned short)s) << 16);
}
__device__ inline unsigned pkbf2(float a, float b) {   // v_cvt_pk_bf16_f32
    __hip_bfloat162 h = __float22bfloat162_rn(make_float2(a, b));
    return *(unsigned*)&h;
}
__device__ inline v8s ldsld8(const short* p) {
    return *(const v8s*)__builtin_assume_aligned(p, 16);
}
__device__ inline void g2lds16(const void* g, void* l) {
    __builtin_amdgcn_global_load_lds(
        (const __attribute__((address_space(1))) unsigned int*)g,
        (__attribute__((address_space(3))) unsigned int*)l, 16, 0, 0);
}

// ---------------------------------------------------------------------------
// Kernel A (fused prep + emis). grid (16, 32), 256 threads, 3 blocks/CU.
// Blocks linear<64: build fragment-linear bf16 weights + exp(trans) tables,
// then release via device-scope flags. All blocks: stage A, spin on flags,
// then MFMA conv + FC with fused softmax-style epilogue.
// ---------------------------------------------------------------------------
__global__ __launch_bounds__(256, 3) void emis_kernel(
    const int* __restrict__ x, const float* __restrict__ emb,
    const float* __restrict__ cw, const float* __restrict__ cb,
    const float* __restrict__ fcw, const float* __restrict__ fcb,
    const float* __restrict__ tr, const int* __restrict__ tags,
    unsigned short* __restrict__ wB2, unsigned short* __restrict__ fcwT2,
    unsigned short* __restrict__ AT, unsigned short* __restrict__ Ab,
    unsigned* __restrict__ flags, unsigned* __restrict__ done,
    float* __restrict__ accum, unsigned* __restrict__ cnt,
    float* __restrict__ expem, float* __restrict__ rmv, float* __restrict__ emtag)
{
    __shared__ __align__(16) short ldsA[34 * AP];       // 22304 B (reused as feat)
    __shared__ __align__(16) short ldsB[CHB];           // 24576 B (weights)

    const int b      = blockIdx.y;
    const int s0     = blockIdx.x * 32;
    const int tid    = threadIdx.x;
    const int wv     = tid >> 6;
    const int lane   = tid & 63;
    const int col    = lane & 15;
    const int q      = lane >> 4;
    const int bofs   = ((col << 2) | q) << 3;
    const int linear = blockIdx.y * 16 + blockIdx.x;

    // ---- prep phase (blocks 0..63) ----
    if (linear < 64) {
        const int gid = linear * 256 + tid;
        const int gs  = 64 * 256;
        for (int idx = gid; idx < NCH * CKS * 8 * 512; idx += gs) {
            int e = idx & 7, p = (idx >> 3) & 63, blk = idx >> 9;
            int ch = blk / 24, rem = blk - ch * 24;
            int sl = rem >> 3, ft = rem & 7;
            int pc = p >> 2, pq = p & 3;
            int n  = ft * 16 + pc;
            int gk = ch * 96 + sl * 32 + pq * 8 + e;
            int kk = gk / 320, ee = gk - kk * 320;
            float v = (n < FF && ee < EE) ? cw[n * 900 + ee * 3 + kk] : 0.f;
            wB2[idx] = f2bf(v);
        }
        for (int idx = gid; idx < 16 * 512; idx += gs) {
            int e = idx & 7, p = (idx >> 3) & 63, blk = idx >> 9;
            int ks = blk >> 2, nt = blk & 3;
            int pc = p >> 2, pq = p & 3;
            int t = nt * 16 + pc, f = ks * 32 + pq * 8 + e;
            float v = (t < TT && f < FF) ? fcw[t * FF + f] : 0.f;
            fcwT2[idx] = f2bf(v);
        }
        for (int idx = gid; idx < 64 * 64; idx += gs) {
            int r = idx >> 6, c2 = idx & 63;
            AT[idx] = (r < TT && c2 < TT) ? f2bf(__expf(tr[c2 * TT + r])) : 0;
            Ab[idx] = (r < TT && c2 < TT) ? f2bf(__expf(tr[r * TT + c2])) : 0;
        }
        __syncthreads();
        if (tid == 0) {
            __threadfence();
            __hip_atomic_store(&flags[linear], MAGICU,
                               __ATOMIC_RELEASE, __HIP_MEMORY_SCOPE_AGENT);
        }
    }
    // zero handshake state for the next kernel (visible at kernel boundary)
    if (linear == 0) {
        if (tid < BB) done[tid] = 0u;
        else if (tid == BB) *accum = 0.f;
        else if (tid == BB + 1) *cnt = 0u;
    }

    // ---- stage A with explicit MLP: all x-loads, then all emb gathers ----
    int   xr[10], ofs[10], e0a[10];
#pragma unroll
    for (int it = 0; it < 10; ++it) {
        int g = tid + it * 256;
        int r = g / 75, eg = g - r * 75;
        int e0 = eg * 4;
        int src = s0 - 1 + r;
        bool v = (g < 2550) && (src >= 0) && (src < SS);
        xr[it]  = v ? x[b * SS + src] : -1;
        ofs[it] = r * AP + e0;
        e0a[it] = e0;
    }
    float4 vv[10];
#pragma unroll
    for (int it = 0; it < 10; ++it)
        vv[it] = (xr[it] >= 0)
               ? *(const float4*)(emb + (size_t)xr[it] * EE + e0a[it])
               : make_float4(0.f, 0.f, 0.f, 0.f);
#pragma unroll
    for (int it = 0; it < 10; ++it) {
        int g = tid + it * 256;
        if (g < 2550) {
            unsigned lo = pkbf2(vv[it].x, vv[it].y);
            unsigned hi = pkbf2(vv[it].z, vv[it].w);
            *(uint2*)&ldsA[ofs[it]] = make_uint2(lo, hi);
        }
    }
    if (tid < 34 * 5) {
        int r = tid / 5, c0 = 300 + (tid % 5) * 4;
        *(short4*)&ldsA[r * AP + c0] = make_short4(0, 0, 0, 0);
    }

    // ---- wait for prep completion, then start weight DMA ----
    if (tid == 0) {
        for (int i = 0; i < 64; ++i)
            while (__hip_atomic_load(&flags[i], __ATOMIC_ACQUIRE,
                                     __HIP_MEMORY_SCOPE_AGENT) != MAGICU) {}
    }
    __syncthreads();
#pragma unroll
    for (int it = 0; it < 6; ++it) {
        int seg = it * 4 + wv;
        g2lds16((const char*)wB2 + seg * 1024 + lane * 16,
                (char*)ldsB + seg * 1024);
    }

    v4f acc[2][2];
#pragma unroll
    for (int a = 0; a < 2; ++a)
#pragma unroll
        for (int f = 0; f < 2; ++f) acc[a][f] = (v4f){0.f, 0.f, 0.f, 0.f};

    const int ftA = wv * 2, ftB = wv * 2 + 1;
    for (int ch = 0; ch < NCH; ++ch) {
        __syncthreads();   // DMA for chunk ch drained (+ A staged on ch=0)
#pragma unroll
        for (int sl = 0; sl < CKS; ++sl) {
            int gk = ch * 96 + sl * 32;
            int kk = (gk >= 640) ? 2 : (gk >= 320 ? 1 : 0);
            int e0 = gk - kk * 320;
            v8s a0 = ldsld8(&ldsA[(col + kk) * AP + e0 + q * 8]);
            v8s a1 = ldsld8(&ldsA[(16 + col + kk) * AP + e0 + q * 8]);
            v8s b0 = ldsld8(&ldsB[((sl * 8 + ftA) << 9) + bofs]);
            v8s b1 = ldsld8(&ldsB[((sl * 8 + ftB) << 9) + bofs]);
            acc[0][0] = MFMA16(a0, b0, acc[0][0], 0, 0, 0);
            acc[0][1] = MFMA16(a0, b1, acc[0][1], 0, 0, 0);
            acc[1][0] = MFMA16(a1, b0, acc[1][0], 0, 0, 0);
            acc[1][1] = MFMA16(a1, b1, acc[1][1], 0, 0, 0);
        }
        __syncthreads();
        if (ch < NCH - 1) {
            const char* g = (const char*)(wB2 + (size_t)(ch + 1) * CHB);
#pragma unroll
            for (int it = 0; it < 6; ++it) {
                int seg = it * 4 + wv;
                g2lds16(g + seg * 1024 + lane * 16, (char*)ldsB + seg * 1024);
            }
        }
    }

    // FC weights DMA into ldsB; feat (bias+relu, bf16) into ldsA (dead)
    short* A2 = ldsA;
    short* B2 = ldsB;
#pragma unroll
    for (int it = 0; it < 4; ++it) {
        int seg = it * 4 + wv;
        g2lds16((const char*)fcwT2 + seg * 1024 + lane * 16,
                (char*)B2 + seg * 1024);
    }
#pragma unroll
    for (int st = 0; st < 2; ++st)
#pragma unroll
        for (int fi = 0; fi < 2; ++fi) {
            int f = (wv * 2 + fi) * 16 + col;
            float bias = (f < FF) ? cb[f] : 0.f;
#pragma unroll
            for (int rg = 0; rg < 4; ++rg) {
                int s = st * 16 + q * 4 + rg;
                float v = (f < FF) ? fmaxf(acc[st][fi][rg] + bias, 0.f) : 0.f;
                A2[s * A2P + f] = (short)f2bf(v);
            }
        }
    __syncthreads();

    if (wv < 2) {
        v4f a2[4];
#pragma unroll
        for (int nt = 0; nt < 4; ++nt) a2[nt] = (v4f){0.f, 0.f, 0.f, 0.f};
#pragma unroll
        for (int ks = 0; ks < 4; ++ks) {
            v8s af = ldsld8(&A2[(wv * 16 + col) * A2P + ks * 32 + q * 8]);
#pragma unroll
            for (int nt = 0; nt < 4; ++nt) {
                v8s bt = ldsld8(&B2[((ks * 4 + nt) << 9) + bofs]);
                a2[nt] = MFMA16(af, bt, a2[nt], 0, 0, 0);
            }
        }
        float fb0 = fcb[col], fb1 = fcb[16 + col], fb2 = fcb[32 + col];
        float fb3 = (col < 2) ? fcb[48 + col] : 0.f;
#pragma unroll
        for (int rg = 0; rg < 4; ++rg) {
            int s = s0 + wv * 16 + q * 4 + rg;
            float e0v = a2[0][rg] + fb0;
            float e1v = a2[1][rg] + fb1;
            float e2v = a2[2][rg] + fb2;
            float e3v = (col < 2) ? a2[3][rg] + fb3 : -1e30f;
            float m = fmaxf(fmaxf(e0v, e1v), fmaxf(e2v, e3v));
#pragma unroll
            for (int off = 1; off < 16; off <<= 1) m = fmaxf(m, __shfl_xor(m, off));
            int gidx = b * SS + s;
            if (col == 0) rmv[gidx] = m;
            int tg = tags[gidx];
            float* orow = expem + (size_t)gidx * TT;
            orow[col]      = __expf(e0v - m);
            orow[16 + col] = __expf(e1v - m);
            orow[32 + col] = __expf(e2v - m);
            if (col < 2) orow[48 + col] = __expf(e3v - m);
            if (tg == col)            emtag[gidx] = e0v;
            else if (tg == 16 + col)  emtag[gidx] = e1v;
            else if (tg == 32 + col)  emtag[gidx] = e2v;
            else if (col < 2 && tg == 48 + col) emtag[gidx] = e3v;
        }
    }
}

// ---------------------------------------------------------------------------
// Kernel B (fused chunk + chain + finish). grid (NC, BB), 64 threads.
// Each block: numerator partial for its s-range + 16-step matrix product.
// Last-arriving block per batch runs the 32-step chain; last batch writes out.
// ---------------------------------------------------------------------------
__global__ __launch_bounds__(64) void chunk_kernel(
    const float* __restrict__ expem, const unsigned short* __restrict__ AT,
    const unsigned short* __restrict__ Ab,
    const float* __restrict__ emtag, const float* __restrict__ rmv,
    const int* __restrict__ tags, const float* __restrict__ tr,
    const float* __restrict__ start, const float* __restrict__ endt,
    unsigned short* __restrict__ R, float* __restrict__ lsR,
    float* __restrict__ part, unsigned* __restrict__ done,
    float* __restrict__ accum, unsigned* __restrict__ cnt,
    float* __restrict__ out)
{
    __shared__ __align__(16) short L[2][64 * MP];
    __shared__ __align__(16) float emL[CH][64];
    const int c = blockIdx.x, b = blockIdx.y;
    const int lane = threadIdx.x;
    const int col = lane & 15, q = lane >> 4;
    const int t0 = c * CH + 1;
    const int nf = (c == NC - 1) ? (SS - 1 - (NC - 1) * CH) : CH;

    // numerator partial for s in [16c, 16c+16): (rmv - emtag) - trans pair
    {
        int s = c * CH + lane;
        float pc = 0.f;
        if (lane < CH) {
            int gi = b * SS + s;
            pc = rmv[gi] - emtag[gi];
            if (s < SS - 1) pc -= tr[tags[gi] * TT + tags[gi + 1]];
        }
#pragma unroll
        for (int off = 1; off < 16; off <<= 1) pc += __shfl_xor(pc, off);
        if (lane == 0) part[b * NC + c] = pc;
    }

    for (int idx = lane; idx < CH * 64; idx += 64) {
        int k = idx >> 6, m = idx & 63;
        float v = 0.f;
        if (m < TT && k < nf) v = expem[((size_t)(b * SS + t0 + k)) * TT + m];
        emL[k][m] = v;
    }

    v8s af[4][2];
#pragma unroll
    for (int jt = 0; jt < 4; ++jt)
#pragma unroll
        for (int kc = 0; kc < 2; ++kc)
            af[jt][kc] = *(const v8s*)(AT + (jt * 16 + col) * 64 + kc * 32 + q * 8);
    __syncthreads();

    {
        const v8s* arow = (const v8s*)(Ab + lane * 64);
#pragma unroll
        for (int g = 0; g < 8; ++g) {
            v8s a = arow[g];
            float f[8];
#pragma unroll
            for (int e = 0; e < 8; ++e) f[e] = bf2f(a[e]) * emL[0][g * 8 + e];
            uint4 o = make_uint4(pkbf2(f[0], f[1]), pkbf2(f[2], f[3]),
                                 pkbf2(f[4], f[5]), pkbf2(f[6], f[7]));
            *(uint4*)&L[0][lane * MP + g * 8] = o;
        }
    }

    int cur = 0;
    for (int k = 1; k < nf; ++k) {
        __syncthreads();
        v8s bf[4][2];
#pragma unroll
        for (int nt = 0; nt < 4; ++nt)
#pragma unroll
            for (int kc = 0; kc < 2; ++kc)
                bf[nt][kc] = ldsld8(&L[cur][(nt * 16 + col) * MP + kc * 32 + q * 8]);
        v4f acc[4][4];
#pragma unroll
        for (int jt = 0; jt < 4; ++jt)
#pragma unroll
            for (int nt = 0; nt < 4; ++nt) {
                acc[jt][nt] = (v4f){0.f, 0.f, 0.f, 0.f};
                acc[jt][nt] = MFMA16(af[jt][0], bf[nt][0], acc[jt][nt], 0, 0, 0);
                acc[jt][nt] = MFMA16(af[jt][1], bf[nt][1], acc[jt][nt], 0, 0, 0);
            }
        if (k < nf - 1) {
#pragma unroll
            for (int jt = 0; jt < 4; ++jt) {
                const float4 em4 = *(const float4*)&emL[k][jt * 16 + q * 4];
#pragma unroll
                for (int nt = 0; nt < 4; ++nt) {
                    uint2 o = make_uint2(
                        pkbf2(acc[jt][nt][0] * em4.x, acc[jt][nt][1] * em4.y),
                        pkbf2(acc[jt][nt][2] * em4.z, acc[jt][nt][3] * em4.w));
                    *(uint2*)&L[cur ^ 1][(nt * 16 + col) * MP + jt * 16 + q * 4] = o;
                }
            }
            cur ^= 1;
        } else {
            float vals[4][4][4];
            float mx = 0.f;
#pragma unroll
            for (int jt = 0; jt < 4; ++jt) {
                const float4 em4 = *(const float4*)&emL[k][jt * 16 + q * 4];
#pragma unroll
                for (int nt = 0; nt < 4; ++nt) {
                    vals[jt][nt][0] = acc[jt][nt][0] * em4.x;
                    vals[jt][nt][1] = acc[jt][nt][1] * em4.y;
                    vals[jt][nt][2] = acc[jt][nt][2] * em4.z;
                    vals[jt][nt][3] = acc[jt][nt][3] * em4.w;
#pragma unroll
                    for (int r = 0; r < 4; ++r) mx = fmaxf(mx, vals[jt][nt][r]);
                }
            }
#pragma unroll
            for (int off = 1; off < 64; off <<= 1) mx = fmaxf(mx, __shfl_xor(mx, off));
            mx = fmaxf(mx, 1e-37f);
            float inv = 1.f / mx;
            unsigned short* Rc = R + ((size_t)(b * NC + c) << 12);
#pragma unroll
            for (int jt = 0; jt < 4; ++jt)
#pragma unroll
                for (int nt = 0; nt < 4; ++nt)
#pragma unroll
                    for (int r = 0; r < 4; ++r)
                        Rc[(jt * 16 + q * 4 + r) * 64 + nt * 16 + col] =
                            f2bf(vals[jt][nt][r] * inv);
            if (lane == 0) lsR[b * NC + c] = __logf(mx);
        }
    }

    // ---- handshake: last block of batch b runs the chain ----
    int old = 0;
    if (lane == 0) {
        __threadfence();
        old = (int)atomicAdd(&done[b], 1u);
    }
    old = __shfl(old, 0);
    if (old != NC - 1) return;
    __threadfence();   // acquire: other blocks' R/lsR/part now visible

    float* pvec = (float*)emL;
    pvec[lane] = (lane < TT) ? __expf(start[lane]) * expem[((size_t)(b * SS)) * TT + lane] : 0.f;
    const unsigned short* Rb = R + ((size_t)(b * NC) << 12);
    v8s rb[3][8];
#pragma unroll
    for (int pc = 0; pc < 3; ++pc)
#pragma unroll
        for (int g = 0; g < 8; ++g)
            rb[pc][g] = *(const v8s*)(Rb + ((size_t)pc << 12) + lane * 64 + g * 8);
    float logacc = 0.f;
#pragma unroll
    for (int cc = 0; cc < NC; ++cc) {
        const int slot = cc % 3;
        float acc = 0.f;
        const float4* pv = (const float4*)pvec;
#pragma unroll
        for (int g = 0; g < 8; ++g) {
            v8s v = rb[slot][g];
            float4 pA = pv[g * 2], pB = pv[g * 2 + 1];
            acc = fmaf(bf2f(v[0]), pA.x, acc);
            acc = fmaf(bf2f(v[1]), pA.y, acc);
            acc = fmaf(bf2f(v[2]), pA.z, acc);
            acc = fmaf(bf2f(v[3]), pA.w, acc);
            acc = fmaf(bf2f(v[4]), pB.x, acc);
            acc = fmaf(bf2f(v[5]), pB.y, acc);
            acc = fmaf(bf2f(v[6]), pB.z, acc);
            acc = fmaf(bf2f(v[7]), pB.w, acc);
        }
        if (cc + 3 < NC) {
            const unsigned short* Rn = Rb + ((size_t)(cc + 3) << 12);
#pragma unroll
            for (int g = 0; g < 8; ++g)
                rb[slot][g] = *(const v8s*)(Rn + lane * 64 + g * 8);
        }
        float mx = acc;
#pragma unroll
        for (int off = 1; off < 64; off <<= 1) mx = fmaxf(mx, __shfl_xor(mx, off));
        mx = fmaxf(mx, 1e-37f);
        logacc += __logf(mx) + lsR[b * NC + cc];
        pvec[lane] = acc * (1.f / mx);
    }
    float sv = (lane < TT) ? pvec[lane] * __expf(endt[lane]) : 0.f;
#pragma unroll
    for (int off = 1; off < 64; off <<= 1) sv += __shfl_xor(sv, off);
    float lz = logacc + __logf(sv);

    float np = (lane < NC) ? part[b * NC + lane] : 0.f;
#pragma unroll
    for (int off = 1; off < 32; off <<= 1) np += __shfl_xor(np, off);

    if (lane == 0) {
        float nll = lz + np - start[tags[b * SS]] - endt[tags[b * SS + SS - 1]];
        atomicAdd(accum, nll);
        __threadfence();
        unsigned o2 = atomicAdd(cnt, 1u);
        if (o2 == BB - 1) out[0] = atomicAdd(accum, 0.f);
    }
}

extern "C" void kernel_launch(void* const* d_in, const int* in_sizes, int n_in,
                              void* d_out, int out_size, void* d_ws, size_t ws_size,
                              hipStream_t stream)
{
    const int*   x    = (const int*)d_in[0];
    const int*   tags = (const int*)d_in[1];
    const float* emb  = (const float*)d_in[2];
    const float* cw   = (const float*)d_in[3];
    const float* cb   = (const float*)d_in[4];
    const float* fcw  = (const float*)d_in[5];
    const float* fcb  = (const float*)d_in[6];
    const float* st   = (const float*)d_in[7];
    const float* en   = (const float*)d_in[8];
    const float* tr   = (const float*)d_in[9];

    unsigned short* wB2   = (unsigned short*)d_ws;            // 122880 sh
    unsigned short* fcwT2 = wB2 + NCH * CKS * 8 * 512;        // 8192 sh
    unsigned short* ATm   = fcwT2 + 16 * 512;                 // 4096 sh
    unsigned short* Abm   = ATm + 4096;                       // 4096 sh
    unsigned short* Rm    = Abm + 4096;                       // 8 MB
    float* fbase   = (float*)(Rm + (size_t)BB * NC * 4096);
    float* expem   = fbase;                                   // 819200
    float* rmv     = expem + (size_t)BB * SS * TT;            // 16384
    float* emtag   = rmv + BB * SS;                           // 16384
    float* lsR     = emtag + BB * SS;                         // 1024
    float* part    = lsR + BB * NC;                           // 1024
    float* accum   = part + BB * NC;                          // 1
    unsigned* cnt  = (unsigned*)(accum + 1);                  // 1
    unsigned* done = cnt + 1;                                 // 32
    unsigned* flags = done + BB;                              // 64

    emis_kernel<<<dim3(16, BB), 256, 0, stream>>>(
        x, emb, cw, cb, fcw, fcb, tr, tags,
        wB2, fcwT2, ATm, Abm, flags, done, accum, cnt,
        expem, rmv, emtag);
    chunk_kernel<<<dim3(NC, BB), 64, 0, stream>>>(
        expem, ATm, Abm, emtag, rmv, tags, tr, st, en,
        Rm, lsR, part, done, accum, cnt, (float*)d_out);
}